// Round 10
// baseline (101.409 us; speedup 1.0000x reference)
//
#include <hip/hip_runtime.h>
#include <math.h>

// Problem constants (fixed by setup_inputs)
#define BTOT 1024
#define NE   16
#define NA   4
#define DD   48        // NE*3
#define HH   512
#define ROWS (BTOT * DD)   // 49152

// Large GEMM tile (mgemm)
#define GBM 128
#define GBN 128
#define GBK 64
#define NCB (HH / GBN)            // 4 column blocks
#define MG  (NCB * (ROWS / GBM))  // 1536 mgemm blocks
#define NU  128                   // u-gemm blocks (run first)
#define NT  (HH / GBK)            // 8 K-tiles

typedef __attribute__((ext_vector_type(8))) short bf16x8;          // 8 bf16 (4 VGPRs)
typedef __attribute__((ext_vector_type(8))) unsigned short u16x8;
typedef __attribute__((ext_vector_type(4))) float f32x4;

__device__ inline unsigned short f2bf(float f) {
  unsigned int u = __builtin_bit_cast(unsigned int, f);
  u += 0x7fffu + ((u >> 16) & 1u);   // round-to-nearest-even
  return (unsigned short)(u >> 16);
}
__device__ inline float bf2f(unsigned short s) {
  unsigned int u = ((unsigned int)s) << 16;
  return __builtin_bit_cast(float, u);
}

// ushort index of 16B chunk `chunk` of row `row` in a [*][64]-bf16 LDS tile,
// XOR-swizzled so stride-128B column reads spread across 8 bank slots (T2).
// Verified: SQ_LDS_BANK_CONFLICT == 0 in R3-R5, R9.
__device__ inline int swz(int row, int chunk) {
  return (row << 6) + ((chunk ^ (row & 7)) << 3);
}

// async global->LDS, 16B per lane; LDS dest = wave-uniform base + lane*16
__device__ inline void gload16(const ushort* g, ushort* l) {
  __builtin_amdgcn_global_load_lds(
      (const __attribute__((address_space(1))) unsigned int*)g,
      (__attribute__((address_space(3))) unsigned int*)l, 16, 0, 0);
}

// ---------------------------------------------------------------------------
// 128x128 GEMM K-loop, double-buffered 2-phase, compiler-visible sync only.
// Per tile: issue next tile's gload_lds into the OTHER LDS half FIRST (they
// land during compute), compute current half, one __syncthreads (drains
// vmcnt+lgkmcnt then s_barrier -> next half ready, current half free).
// NOTE: R6/R7 "races" of this structure were actually a workspace-overlap
// bug (see layout comment at kernel_launch); this is the clean A/B re-test
// on the verified-green R9 baseline.
// Pre-swizzled global source: LDS slot (row, chunk c) holds global chunk
// c^(row&7); lane l of issue q -> row=q*8+(l>>3), fetches chunk (l&7)^(l>>3).
// ---------------------------------------------------------------------------
__device__ inline void gemm128_k_loop(const ushort* __restrict__ abase,
                                      const ushort* __restrict__ bbase,
                                      ushort* As, ushort* Bs,
                                      int w, int l, f32x4 acc[4][4]) {
  const int lrow = l >> 3;
  const int cg = (l & 7) ^ lrow;
  const ushort* __restrict__ ap = abase + (w * 32 + lrow) * HH + cg * 8;
  const ushort* __restrict__ bp = bbase + (w * 32 + lrow) * HH + cg * 8;
  const int wm = w >> 1, wn = w & 1;
  const int lr = l & 15, lg = l >> 4;

  // prologue: stage K-tile 0 into half 0
#pragma unroll
  for (int q = 0; q < 4; ++q) {
    gload16(ap + q * 8 * HH, As + (w * 4 + q) * 512);
    gload16(bp + q * 8 * HH, Bs + (w * 4 + q) * 512);
  }
  __syncthreads();

  for (int kt = 0; kt < NT; ++kt) {
    const int cur = (kt & 1) << 13;   // *8192 ushorts
    if (kt + 1 < NT) {
      const int nxt = ((kt + 1) & 1) << 13;
      const int koff = (kt + 1) * GBK;
#pragma unroll
      for (int q = 0; q < 4; ++q) {
        gload16(ap + koff + q * 8 * HH, As + nxt + (w * 4 + q) * 512);
        gload16(bp + koff + q * 8 * HH, Bs + nxt + (w * 4 + q) * 512);
      }
    }
#pragma unroll
    for (int k0 = 0; k0 < GBK; k0 += 32) {
      const int ck = (k0 >> 3) + lg;
      bf16x8 af[4], bfr[4];
#pragma unroll
      for (int m = 0; m < 4; ++m)
        af[m] = *reinterpret_cast<const bf16x8*>(
            &As[cur + swz(wm * 64 + m * 16 + lr, ck)]);
#pragma unroll
      for (int n = 0; n < 4; ++n)
        bfr[n] = *reinterpret_cast<const bf16x8*>(
            &Bs[cur + swz(wn * 64 + n * 16 + lr, ck)]);
#pragma unroll
      for (int m = 0; m < 4; ++m)
#pragma unroll
        for (int n = 0; n < 4; ++n)
          acc[m][n] = __builtin_amdgcn_mfma_f32_16x16x32_bf16(af[m], bfr[n],
                                                              acc[m][n], 0, 0, 0);
    }
    __syncthreads();
  }
}

// ---------------------------------------------------------------------------
// 64x64 GEMM K-loop, same dbuf 2-phase. Half = 4096 ushorts.
// ---------------------------------------------------------------------------
__device__ inline void gemm64_k_loop(const ushort* __restrict__ abase,
                                     const ushort* __restrict__ bbase,
                                     ushort* As, ushort* Bs,
                                     int w, int l, f32x4 acc[2][2]) {
  const int lrow = l >> 3;
  const int cg = (l & 7) ^ lrow;
  const ushort* __restrict__ ap = abase + (w * 16 + lrow) * HH + cg * 8;
  const ushort* __restrict__ bp = bbase + (w * 16 + lrow) * HH + cg * 8;
  const int wm = w >> 1, wn = w & 1;
  const int lr = l & 15, lg = l >> 4;

#pragma unroll
  for (int q = 0; q < 2; ++q) {
    gload16(ap + q * 8 * HH, As + (w * 2 + q) * 512);
    gload16(bp + q * 8 * HH, Bs + (w * 2 + q) * 512);
  }
  __syncthreads();

  for (int kt = 0; kt < NT; ++kt) {
    const int cur = (kt & 1) << 12;   // *4096 ushorts
    if (kt + 1 < NT) {
      const int nxt = ((kt + 1) & 1) << 12;
      const int koff = (kt + 1) * GBK;
#pragma unroll
      for (int q = 0; q < 2; ++q) {
        gload16(ap + koff + q * 8 * HH, As + nxt + (w * 2 + q) * 512);
        gload16(bp + koff + q * 8 * HH, Bs + nxt + (w * 2 + q) * 512);
      }
    }
#pragma unroll
    for (int k0 = 0; k0 < GBK; k0 += 32) {
      const int ck = (k0 >> 3) + lg;
      bf16x8 af[2], bfr[2];
#pragma unroll
      for (int m = 0; m < 2; ++m)
        af[m] = *reinterpret_cast<const bf16x8*>(
            &As[cur + swz(wm * 32 + m * 16 + lr, ck)]);
#pragma unroll
      for (int n = 0; n < 2; ++n)
        bfr[n] = *reinterpret_cast<const bf16x8*>(
            &Bs[cur + swz(wn * 32 + n * 16 + lr, ck)]);
#pragma unroll
      for (int m = 0; m < 2; ++m)
#pragma unroll
        for (int n = 0; n < 2; ++n)
          acc[m][n] = __builtin_amdgcn_mfma_f32_16x16x32_bf16(af[m], bfr[n],
                                                              acc[m][n], 0, 0, 0);
    }
    __syncthreads();
  }
}

// ---------------------------------------------------------------------------
// K1: per-sample layer 1 + Ab panel build + potential; blocks < 256 also
//     convert one 32x32 W2 tile -> W2b / W2Tb.
// ---------------------------------------------------------------------------
__global__ __launch_bounds__(256) void k_l1pot(
    const float* __restrict__ X, const float* __restrict__ ATOM,
    const float* __restrict__ Z, const float* __restrict__ W1,
    const float* __restrict__ B1, const float* __restrict__ W2,
    ushort* __restrict__ W2b, ushort* __restrict__ W2Tb,
    ushort* __restrict__ T1b, float* __restrict__ D1,
    ushort* __restrict__ Ab, float* __restrict__ POT) {
  const int b = blockIdx.x, tid = threadIdx.x;
  __shared__ float xs[DD];
  __shared__ float d1s[HH];
  __shared__ float red[256];
  __shared__ float tile[32][33];

  // ---- fused W2 conversion (one 32x32 tile per block for b < 256)
  if (b < 256) {
    const int bx = (b & 15) * 32, by = (b >> 4) * 32;
    const int tx = tid & 31, ty = tid >> 5;  // ty 0..7
    for (int r = 0; r < 32; r += 8) {
      float v = W2[(by + ty + r) * HH + bx + tx];
      tile[ty + r][tx] = v;
      W2b[(by + ty + r) * HH + bx + tx] = f2bf(v);
    }
    __syncthreads();
    for (int r = 0; r < 32; r += 8)
      W2Tb[(bx + ty + r) * HH + by + tx] = f2bf(tile[tx][ty + r]);
  }

  if (tid < DD) xs[tid] = X[b * DD + tid];
  __syncthreads();

  // ---- layer 1: a1 = x@W1 + b1 ; two j per thread
  {
    const int j0 = tid * 2;
    float acc0 = B1[j0], acc1 = B1[j0 + 1];
#pragma unroll 8
    for (int i = 0; i < DD; ++i) {
      float xv = xs[i];
      float2 w = *reinterpret_cast<const float2*>(&W1[i * HH + j0]);
      acc0 = fmaf(xv, w.x, acc0);
      acc1 = fmaf(xv, w.y, acc1);
    }
    float t0 = tanhf(acc0), t1v = tanhf(acc1);
    unsigned int pk = ((unsigned int)f2bf(t1v) << 16) | f2bf(t0);
    *reinterpret_cast<unsigned int*>(&T1b[b * HH + j0]) = pk;
    float dd0 = 1.f - t0 * t0, dd1 = 1.f - t1v * t1v;
    d1s[j0] = dd0; d1s[j0 + 1] = dd1;
    *reinterpret_cast<float2*>(&D1[b * HH + j0]) = make_float2(dd0, dd1);
  }
  __syncthreads();

  // ---- Ab panel: Ab[b*48+i][k] = bf16(W1[i,k]*d1[k]); thread covers k=2*tid
  {
    const int k0 = tid * 2;
    const float dd0 = d1s[k0], dd1 = d1s[k0 + 1];
#pragma unroll 4
    for (int i = 0; i < DD; ++i) {
      float2 w = *reinterpret_cast<const float2*>(&W1[i * HH + k0]);
      unsigned int pk =
          ((unsigned int)f2bf(w.y * dd1) << 16) | f2bf(w.x * dd0);
      *reinterpret_cast<unsigned int*>(&Ab[(b * DD + i) * HH + k0]) = pk;
    }
  }

  // ---- potential (deterministic tree reduction)
  {
    float p = 0.f;
    for (int pr = tid; pr < NE * (NE - 1) / 2; pr += 256) {
      int i = 0, rem = pr;
      while (rem >= NE - 1 - i) { rem -= NE - 1 - i; ++i; }
      int j = i + 1 + rem;
      float dx = xs[i * 3 + 0] - xs[j * 3 + 0];
      float dy = xs[i * 3 + 1] - xs[j * 3 + 1];
      float dz = xs[i * 3 + 2] - xs[j * 3 + 2];
      float r = fmaxf(sqrtf(dx * dx + dy * dy + dz * dz), 1e-10f);
      p += 1.f / r;
    }
    for (int idx = tid; idx < NE * NA; idx += 256) {
      int e = idx / NA, a = idx % NA;
      float dx = xs[e * 3 + 0] - ATOM[a * 3 + 0];
      float dy = xs[e * 3 + 1] - ATOM[a * 3 + 1];
      float dz = xs[e * 3 + 2] - ATOM[a * 3 + 2];
      float r = fmaxf(sqrtf(dx * dx + dy * dy + dz * dz), 1e-10f);
      p -= Z[a] / r;
    }
    if (tid == 0) {
      for (int a = 0; a < NA; ++a)
        for (int a2 = a + 1; a2 < NA; ++a2) {
          float dx = ATOM[a * 3 + 0] - ATOM[a2 * 3 + 0];
          float dy = ATOM[a * 3 + 1] - ATOM[a2 * 3 + 1];
          float dz = ATOM[a * 3 + 2] - ATOM[a2 * 3 + 2];
          float r = sqrtf(dx * dx + dy * dy + dz * dz);
          if (r > 1e-10f) p += Z[a] * Z[a2] / r;
        }
    }
    red[tid] = p;
    __syncthreads();
    for (int s = 128; s > 0; s >>= 1) {
      if (tid < s) red[tid] += red[tid + s];
      __syncthreads();
    }
    if (tid == 0) POT[b] = fminf(fmaxf(red[0], -1000.f), 1000.f);
  }
}

// ---------------------------------------------------------------------------
// K2: A2 = T1b @ W2 (B = W2Tb), 64x64 tiles, grid 128; epilogue t2/d2:
//   C2[b][k] = -2*t2*d2*w3[k] (fp32), Vb[b][k] = bf16(w3[k]*d2)
// ---------------------------------------------------------------------------
__global__ __launch_bounds__(256) void k_act64(
    const ushort* __restrict__ Ab, const ushort* __restrict__ Bb,
    const float* __restrict__ B2, const float* __restrict__ w3,
    float* __restrict__ C2, ushort* __restrict__ Vb) {
  const int rb = blockIdx.x >> 3;     // 0..15
  const int cb = blockIdx.x & 7;      // 0..7
  const int row0 = rb * 64, col0 = cb * 64;
  const int t = threadIdx.x, w = t >> 6, l = t & 63;

  __shared__ ushort As[2 * 64 * GBK];
  __shared__ ushort Bs[2 * 64 * GBK];

  f32x4 acc[2][2];
#pragma unroll
  for (int m = 0; m < 2; ++m)
#pragma unroll
    for (int n = 0; n < 2; ++n) acc[m][n] = (f32x4)0.f;

  gemm64_k_loop(Ab + row0 * HH, Bb + col0 * HH, As, Bs, w, l, acc);

  const int wm = w >> 1, wn = w & 1, lr = l & 15, lg = l >> 4;
#pragma unroll
  for (int m = 0; m < 2; ++m)
#pragma unroll
    for (int e = 0; e < 4; ++e) {
      const int row = row0 + wm * 32 + m * 16 + lg * 4 + e;
#pragma unroll
      for (int n = 0; n < 2; ++n) {
        const int col = col0 + wn * 32 + n * 16 + lr;
        float a2 = acc[m][n][e] + B2[col];
        float t2 = tanhf(a2);
        float d2 = 1.f - t2 * t2;
        float w3v = w3[col];
        C2[row * HH + col] = -2.f * t2 * d2 * w3v;
        Vb[row * HH + col] = f2bf(w3v * d2);
      }
    }
}

// ---------------------------------------------------------------------------
// K3 (merged): blocks 0..NU-1 run the U-GEMM (64x64) first; blocks NU..
//   run the big m-GEMM (bijective XCD swizzle, cb fastest so the 4
//   col-blocks of one A-panel share L2). Outputs disjoint; all inputs from
//   earlier launches -> dispatch-order safe.
// ---------------------------------------------------------------------------
__global__ __launch_bounds__(256) void k_mu(
    const ushort* __restrict__ Abig, const ushort* __restrict__ W2Tb,
    const float* __restrict__ C2, float* __restrict__ HD2P,
    const ushort* __restrict__ Vb, const ushort* __restrict__ W2b,
    const float* __restrict__ D1, const ushort* __restrict__ T1b,
    float* __restrict__ S1, ushort* __restrict__ C1b) {
  const int t = threadIdx.x, w = t >> 6, l = t & 63;
  __shared__ ushort As[2 * GBM * GBK];   // 32KB
  __shared__ ushort Bs[2 * GBN * GBK];   // 32KB

  if (blockIdx.x < NU) {
    // ---- U-GEMM role: U = Vb @ W2^T (B = W2b), 64x64 tiles
    const int ub = blockIdx.x;          // 0..127
    const int rb = ub >> 3, cb = ub & 7;
    const int row0 = rb * 64, col0 = cb * 64;

    f32x4 acc[2][2];
#pragma unroll
    for (int m = 0; m < 2; ++m)
#pragma unroll
      for (int n = 0; n < 2; ++n) acc[m][n] = (f32x4)0.f;

    gemm64_k_loop(Vb + row0 * HH, W2b + col0 * HH, As, Bs, w, l, acc);

    const int wm = w >> 1, wn = w & 1, lr = l & 15, lg = l >> 4;
#pragma unroll
    for (int m = 0; m < 2; ++m)
#pragma unroll
      for (int e = 0; e < 4; ++e) {
        const int row = row0 + wm * 32 + m * 16 + lg * 4 + e;
#pragma unroll
        for (int n = 0; n < 2; ++n) {
          const int col = col0 + wn * 32 + n * 16 + lr;
          float u = acc[m][n][e];
          float d1 = D1[row * HH + col];
          float t1 = bf2f(T1b[row * HH + col]);
          S1[row * HH + col] = d1 * u;                    // fp32 (gsq accuracy)
          C1b[row * HH + col] = f2bf(-2.f * t1 * d1 * u); // bf16 (clipped later)
        }
      }
  } else {
    // ---- m-GEMM role: M[49152,512] = Abig @ W2, fused c2*m^2 epilogue
    const int bid = blockIdx.x - NU;                      // 0..MG-1
    const int wgid = (bid & 7) * (MG / 8) + (bid >> 3);   // 1536 % 8 == 0
    const int cb = wgid & 3;
    const int rb = wgid >> 2;
    const int row0 = rb * GBM, col0 = cb * GBN;

    f32x4 acc[4][4];
#pragma unroll
    for (int m = 0; m < 4; ++m)
#pragma unroll
      for (int n = 0; n < 4; ++n) acc[m][n] = (f32x4)0.f;

    gemm128_k_loop(Abig + row0 * HH, W2Tb + col0 * HH, As, Bs, w, l, acc);

    const int wm = w >> 1, wn = w & 1, lr = l & 15, lg = l >> 4;
#pragma unroll
    for (int m = 0; m < 4; ++m) {
#pragma unroll
      for (int e = 0; e < 4; ++e) {
        const int row_g = row0 + wm * 64 + m * 16 + lg * 4 + e;
        const int bs2 = row_g / DD;
        const float* __restrict__ c2p = &C2[bs2 * HH + col0 + wn * 64 + lr];
        float s = 0.f;
#pragma unroll
        for (int n = 0; n < 4; ++n) {
          float mv = acc[m][n][e];
          s = fmaf(c2p[n * 16] * mv, mv, s);
        }
        s += __shfl_xor(s, 1);
        s += __shfl_xor(s, 2);
        s += __shfl_xor(s, 4);
        s += __shfl_xor(s, 8);
        if (lr == 0) HD2P[cb * ROWS + row_g] = s;
      }
    }
  }
}

// ---------------------------------------------------------------------------
// K4: per-sample grad/hdiag reduce + finalize (fp32 S1, bf16 C1)
// ---------------------------------------------------------------------------
__global__ __launch_bounds__(256) void k_grad_fin(
    const float* __restrict__ W1, const float* __restrict__ S1,
    const ushort* __restrict__ C1b, const float* __restrict__ HD2P,
    const float* __restrict__ POT, float* __restrict__ OUT) {
  const int b = blockIdx.x, tid = threadIdx.x;
  __shared__ float gtmp[DD], htmp[DD];
  const int wid = tid >> 6, lane = tid & 63;
  const int j0 = lane * 8;   // 64 lanes x 8 = 512

  for (int i = wid; i < DD; i += 4) {
    float4 wa = *reinterpret_cast<const float4*>(&W1[i * HH + j0]);
    float4 wb = *reinterpret_cast<const float4*>(&W1[i * HH + j0 + 4]);
    float4 sa = *reinterpret_cast<const float4*>(&S1[b * HH + j0]);
    float4 sb = *reinterpret_cast<const float4*>(&S1[b * HH + j0 + 4]);
    u16x8 cv = *reinterpret_cast<const u16x8*>(&C1b[b * HH + j0]);
    float wv[8] = {wa.x, wa.y, wa.z, wa.w, wb.x, wb.y, wb.z, wb.w};
    float sv[8] = {sa.x, sa.y, sa.z, sa.w, sb.x, sb.y, sb.z, sb.w};
    float gp = 0.f, hp = 0.f;
#pragma unroll
    for (int e = 0; e < 8; ++e) {
      gp = fmaf(wv[e], sv[e], gp);
      hp = fmaf(wv[e] * wv[e], bf2f(cv[e]), hp);
    }
#pragma unroll
    for (int off = 32; off > 0; off >>= 1) {
      gp += __shfl_down(gp, off);
      hp += __shfl_down(hp, off);
    }
    if (lane == 0) { gtmp[i] = gp; htmp[i] = hp; }
  }
  __syncthreads();

  if (tid < 64) {
    float gv = 0.f, hv = 0.f;
    if (tid < DD) {
      gv = gtmp[tid];
      float h = htmp[tid];
#pragma unroll
      for (int c = 0; c < NCB; ++c) h += HD2P[c * ROWS + b * DD + tid];
      if (h >= -1e30f && h <= 1e30f) h = fminf(fmaxf(h, -50.f), 50.f);
      else h = 0.f;
      hv = h;
    }
    float sq = gv * gv;
#pragma unroll
    for (int off = 32; off > 0; off >>= 1) {
      sq += __shfl_down(sq, off);
      hv += __shfl_down(hv, off);
    }
    if (tid == 0) {
      float kin = fminf(fmaxf(-0.5f * (hv + sq), -100.f), 100.f);
      OUT[b] = kin + POT[b];
    }
  }
}

// ---------------------------------------------------------------------------
// Workspace layout — sizes in FLOAT-SLOTS, non-overlapping (verified R9).
//   W2b   @       0  (131072 fl = 512*512 ush)
//   W2Tb  @  131072  (131072)
//   T1b   @  262144  (262144 fl = 1024*512 ush)
//   Vb    @  524288  (262144)
//   C1b   @  786432  (262144)
//   S1    @ 1048576  (524288 fl fp32)
//   D1    @ 1572864  (524288)
//   C2    @ 2097152  (524288)
//   POT   @ 2621440  (1024)
//   HD2P  @ 2622464  (196608)
//   Abig  @ 2819072  (12582912 fl = 49152*512 ush)   end: 15401984 fl = 61.6MB
// ---------------------------------------------------------------------------
extern "C" void kernel_launch(void* const* d_in, const int* in_sizes, int n_in,
                              void* d_out, int out_size, void* d_ws, size_t ws_size,
                              hipStream_t stream) {
  const float* X    = (const float*)d_in[0];  // [1024,16,3]
  const float* ATOM = (const float*)d_in[1];  // [4,3]
  const float* Z    = (const float*)d_in[2];  // [4]
  const float* W1   = (const float*)d_in[3];  // [48,512]
  const float* B1   = (const float*)d_in[4];  // [512]
  const float* W2   = (const float*)d_in[5];  // [512,512]
  const float* B2   = (const float*)d_in[6];  // [512]
  const float* w3   = (const float*)d_in[7];  // [512]
  float* out = (float*)d_out;

  float* ws = (float*)d_ws;
  ushort* W2b  = (ushort*)(ws + 0);
  ushort* W2Tb = (ushort*)(ws + 131072);
  ushort* T1b  = (ushort*)(ws + 262144);
  ushort* Vb   = (ushort*)(ws + 524288);
  ushort* C1b  = (ushort*)(ws + 786432);
  float*  S1   = ws + 1048576;
  float*  D1   = ws + 1572864;
  float*  C2   = ws + 2097152;
  float*  POT  = ws + 2621440;
  float*  HD2P = ws + 2622464;
  ushort* Abig = (ushort*)(ws + 2819072);

  k_l1pot<<<BTOT, 256, 0, stream>>>(X, ATOM, Z, W1, B1, W2, W2b, W2Tb,
                                    T1b, D1, Abig, POT);
  k_act64<<<128, 256, 0, stream>>>(T1b, W2Tb, B2, w3, C2, Vb);
  k_mu<<<NU + MG, 256, 0, stream>>>(Abig, W2Tb, C2, HD2P,
                                    Vb, W2b, D1, T1b, S1, C1b);
  k_grad_fin<<<BTOT, 256, 0, stream>>>(W1, S1, C1b, HD2P, POT, out);
}

// Round 11
// 99.315 us; speedup vs baseline: 1.0211x; 1.0211x over previous
//
#include <hip/hip_runtime.h>
#include <math.h>

// Problem constants (fixed by setup_inputs)
#define BTOT 1024
#define NE   16
#define NA   4
#define DD   48        // NE*3
#define HH   512
#define ROWS (BTOT * DD)   // 49152

// mgemm tile: 256(M) x 128(N), BK=64, 8 waves x (64x64)
#define GBM2 256
#define GBN  128
#define GBK  64
#define NCB  (HH / GBN)             // 4 column blocks
#define MG2  (NCB * (ROWS / GBM2))  // 768 mgemm blocks
#define NU   128                    // u-gemm blocks (dispatched first)
#define NT   (HH / GBK)             // 8 K-tiles

typedef __attribute__((ext_vector_type(8))) short bf16x8;          // 8 bf16 (4 VGPRs)
typedef __attribute__((ext_vector_type(8))) unsigned short u16x8;
typedef __attribute__((ext_vector_type(4))) float f32x4;

__device__ inline unsigned short f2bf(float f) {
  unsigned int u = __builtin_bit_cast(unsigned int, f);
  u += 0x7fffu + ((u >> 16) & 1u);   // round-to-nearest-even
  return (unsigned short)(u >> 16);
}
__device__ inline float bf2f(unsigned short s) {
  unsigned int u = ((unsigned int)s) << 16;
  return __builtin_bit_cast(float, u);
}

// ushort index of 16B chunk `chunk` of row `row` in a [*][64]-bf16 LDS tile,
// XOR-swizzled so stride-128B column reads spread across 8 bank slots (T2).
// Verified: SQ_LDS_BANK_CONFLICT == 0 in R3-R5, R9, R10.
__device__ inline int swz(int row, int chunk) {
  return (row << 6) + ((chunk ^ (row & 7)) << 3);
}

// async global->LDS, 16B per lane; LDS dest = wave-uniform base + lane*16
__device__ inline void gload16(const ushort* g, ushort* l) {
  __builtin_amdgcn_global_load_lds(
      (const __attribute__((address_space(1))) unsigned int*)g,
      (__attribute__((address_space(3))) unsigned int*)l, 16, 0, 0);
}

// ---------------------------------------------------------------------------
// 64x64 GEMM K-loop (4 waves x 32x32), dbuf 2-phase, __syncthreads only.
// (R10-verified green.) Half = 4096 ushorts.
// ---------------------------------------------------------------------------
__device__ inline void gemm64_k_loop(const ushort* __restrict__ abase,
                                     const ushort* __restrict__ bbase,
                                     ushort* As, ushort* Bs,
                                     int w, int l, f32x4 acc[2][2]) {
  const int lrow = l >> 3;
  const int cg = (l & 7) ^ lrow;
  const ushort* __restrict__ ap = abase + (w * 16 + lrow) * HH + cg * 8;
  const ushort* __restrict__ bp = bbase + (w * 16 + lrow) * HH + cg * 8;
  const int wm = w >> 1, wn = w & 1;
  const int lr = l & 15, lg = l >> 4;

#pragma unroll
  for (int q = 0; q < 2; ++q) {
    gload16(ap + q * 8 * HH, As + (w * 2 + q) * 512);
    gload16(bp + q * 8 * HH, Bs + (w * 2 + q) * 512);
  }
  __syncthreads();

  for (int kt = 0; kt < NT; ++kt) {
    const int cur = (kt & 1) << 12;
    if (kt + 1 < NT) {
      const int nxt = ((kt + 1) & 1) << 12;
      const int koff = (kt + 1) * GBK;
#pragma unroll
      for (int q = 0; q < 2; ++q) {
        gload16(ap + koff + q * 8 * HH, As + nxt + (w * 2 + q) * 512);
        gload16(bp + koff + q * 8 * HH, Bs + nxt + (w * 2 + q) * 512);
      }
    }
#pragma unroll
    for (int k0 = 0; k0 < GBK; k0 += 32) {
      const int ck = (k0 >> 3) + lg;
      bf16x8 af[2], bfr[2];
#pragma unroll
      for (int m = 0; m < 2; ++m)
        af[m] = *reinterpret_cast<const bf16x8*>(
            &As[cur + swz(wm * 32 + m * 16 + lr, ck)]);
#pragma unroll
      for (int n = 0; n < 2; ++n)
        bfr[n] = *reinterpret_cast<const bf16x8*>(
            &Bs[cur + swz(wn * 32 + n * 16 + lr, ck)]);
#pragma unroll
      for (int m = 0; m < 2; ++m)
#pragma unroll
        for (int n = 0; n < 2; ++n)
          acc[m][n] = __builtin_amdgcn_mfma_f32_16x16x32_bf16(af[m], bfr[n],
                                                              acc[m][n], 0, 0, 0);
    }
    __syncthreads();
  }
}

// ---------------------------------------------------------------------------
// K1: per-sample layer 1 + Ab panel build + potential; blocks < 256 also
//     convert one 32x32 W2 tile -> W2b / W2Tb.
// ---------------------------------------------------------------------------
__global__ __launch_bounds__(256) void k_l1pot(
    const float* __restrict__ X, const float* __restrict__ ATOM,
    const float* __restrict__ Z, const float* __restrict__ W1,
    const float* __restrict__ B1, const float* __restrict__ W2,
    ushort* __restrict__ W2b, ushort* __restrict__ W2Tb,
    ushort* __restrict__ T1b, float* __restrict__ D1,
    ushort* __restrict__ Ab, float* __restrict__ POT) {
  const int b = blockIdx.x, tid = threadIdx.x;
  __shared__ float xs[DD];
  __shared__ float d1s[HH];
  __shared__ float red[256];
  __shared__ float tile[32][33];

  if (b < 256) {
    const int bx = (b & 15) * 32, by = (b >> 4) * 32;
    const int tx = tid & 31, ty = tid >> 5;  // ty 0..7
    for (int r = 0; r < 32; r += 8) {
      float v = W2[(by + ty + r) * HH + bx + tx];
      tile[ty + r][tx] = v;
      W2b[(by + ty + r) * HH + bx + tx] = f2bf(v);
    }
    __syncthreads();
    for (int r = 0; r < 32; r += 8)
      W2Tb[(bx + ty + r) * HH + by + tx] = f2bf(tile[tx][ty + r]);
  }

  if (tid < DD) xs[tid] = X[b * DD + tid];
  __syncthreads();

  // ---- layer 1: a1 = x@W1 + b1 ; two j per thread
  {
    const int j0 = tid * 2;
    float acc0 = B1[j0], acc1 = B1[j0 + 1];
#pragma unroll 8
    for (int i = 0; i < DD; ++i) {
      float xv = xs[i];
      float2 w = *reinterpret_cast<const float2*>(&W1[i * HH + j0]);
      acc0 = fmaf(xv, w.x, acc0);
      acc1 = fmaf(xv, w.y, acc1);
    }
    float t0 = tanhf(acc0), t1v = tanhf(acc1);
    unsigned int pk = ((unsigned int)f2bf(t1v) << 16) | f2bf(t0);
    *reinterpret_cast<unsigned int*>(&T1b[b * HH + j0]) = pk;
    float dd0 = 1.f - t0 * t0, dd1 = 1.f - t1v * t1v;
    d1s[j0] = dd0; d1s[j0 + 1] = dd1;
    *reinterpret_cast<float2*>(&D1[b * HH + j0]) = make_float2(dd0, dd1);
  }
  __syncthreads();

  // ---- Ab panel: Ab[b*48+i][k] = bf16(W1[i,k]*d1[k])
  {
    const int k0 = tid * 2;
    const float dd0 = d1s[k0], dd1 = d1s[k0 + 1];
#pragma unroll 4
    for (int i = 0; i < DD; ++i) {
      float2 w = *reinterpret_cast<const float2*>(&W1[i * HH + k0]);
      unsigned int pk =
          ((unsigned int)f2bf(w.y * dd1) << 16) | f2bf(w.x * dd0);
      *reinterpret_cast<unsigned int*>(&Ab[(b * DD + i) * HH + k0]) = pk;
    }
  }

  // ---- potential (deterministic tree reduction)
  {
    float p = 0.f;
    for (int pr = tid; pr < NE * (NE - 1) / 2; pr += 256) {
      int i = 0, rem = pr;
      while (rem >= NE - 1 - i) { rem -= NE - 1 - i; ++i; }
      int j = i + 1 + rem;
      float dx = xs[i * 3 + 0] - xs[j * 3 + 0];
      float dy = xs[i * 3 + 1] - xs[j * 3 + 1];
      float dz = xs[i * 3 + 2] - xs[j * 3 + 2];
      float r = fmaxf(sqrtf(dx * dx + dy * dy + dz * dz), 1e-10f);
      p += 1.f / r;
    }
    for (int idx = tid; idx < NE * NA; idx += 256) {
      int e = idx / NA, a = idx % NA;
      float dx = xs[e * 3 + 0] - ATOM[a * 3 + 0];
      float dy = xs[e * 3 + 1] - ATOM[a * 3 + 1];
      float dz = xs[e * 3 + 2] - ATOM[a * 3 + 2];
      float r = fmaxf(sqrtf(dx * dx + dy * dy + dz * dz), 1e-10f);
      p -= Z[a] / r;
    }
    if (tid == 0) {
      for (int a = 0; a < NA; ++a)
        for (int a2 = a + 1; a2 < NA; ++a2) {
          float dx = ATOM[a * 3 + 0] - ATOM[a2 * 3 + 0];
          float dy = ATOM[a * 3 + 1] - ATOM[a2 * 3 + 1];
          float dz = ATOM[a * 3 + 2] - ATOM[a2 * 3 + 2];
          float r = sqrtf(dx * dx + dy * dy + dz * dz);
          if (r > 1e-10f) p += Z[a] * Z[a2] / r;
        }
    }
    red[tid] = p;
    __syncthreads();
    for (int s = 128; s > 0; s >>= 1) {
      if (tid < s) red[tid] += red[tid + s];
      __syncthreads();
    }
    if (tid == 0) POT[b] = fminf(fmaxf(red[0], -1000.f), 1000.f);
  }
}

// ---------------------------------------------------------------------------
// K2: A2 = T1b @ W2 (B = W2Tb), 64x64 tiles, grid 128; epilogue t2/d2.
// ---------------------------------------------------------------------------
__global__ __launch_bounds__(256) void k_act64(
    const ushort* __restrict__ Ab, const ushort* __restrict__ Bb,
    const float* __restrict__ B2, const float* __restrict__ w3,
    float* __restrict__ C2, ushort* __restrict__ Vb) {
  const int rb = blockIdx.x >> 3;     // 0..15
  const int cb = blockIdx.x & 7;      // 0..7
  const int row0 = rb * 64, col0 = cb * 64;
  const int t = threadIdx.x, w = t >> 6, l = t & 63;

  __shared__ ushort As[2 * 64 * GBK];
  __shared__ ushort Bs[2 * 64 * GBK];

  f32x4 acc[2][2];
#pragma unroll
  for (int m = 0; m < 2; ++m)
#pragma unroll
    for (int n = 0; n < 2; ++n) acc[m][n] = (f32x4)0.f;

  gemm64_k_loop(Ab + row0 * HH, Bb + col0 * HH, As, Bs, w, l, acc);

  const int wm = w >> 1, wn = w & 1, lr = l & 15, lg = l >> 4;
#pragma unroll
  for (int m = 0; m < 2; ++m)
#pragma unroll
    for (int e = 0; e < 4; ++e) {
      const int row = row0 + wm * 32 + m * 16 + lg * 4 + e;
#pragma unroll
      for (int n = 0; n < 2; ++n) {
        const int col = col0 + wn * 32 + n * 16 + lr;
        float a2 = acc[m][n][e] + B2[col];
        float t2 = tanhf(a2);
        float d2 = 1.f - t2 * t2;
        float w3v = w3[col];
        C2[row * HH + col] = -2.f * t2 * d2 * w3v;
        Vb[row * HH + col] = f2bf(w3v * d2);
      }
    }
}

// ---------------------------------------------------------------------------
// K3 (merged, 512 threads): blocks 0..NU-1 = U-GEMM 64x64 with 8 waves
// (wave = 32x16 patch); blocks NU.. = m-GEMM 256x128 tiles, 8 waves x 64x64
// (per-wave code identical to the verified 128x128 kernel; only the staging
// map scales). Sync = dbuf 2-phase with __syncthreads only (R10-verified).
// 768 mgemm blocks = exactly 3 rounds at 1 block/CU (96KB LDS).
// ---------------------------------------------------------------------------
__global__ __launch_bounds__(512) void k_mu(
    const ushort* __restrict__ Abig, const ushort* __restrict__ W2Tb,
    const float* __restrict__ C2, float* __restrict__ HD2P,
    const ushort* __restrict__ Vb, const ushort* __restrict__ W2b,
    const float* __restrict__ D1, const ushort* __restrict__ T1b,
    float* __restrict__ S1, ushort* __restrict__ C1b) {
  const int t = threadIdx.x, w = t >> 6, l = t & 63;
  __shared__ ushort As[2 * GBM2 * GBK];   // 64KB (halves of 16384 ush)
  __shared__ ushort Bs[2 * GBN * GBK];    // 32KB (halves of 8192 ush)

  const int lrow = l >> 3;
  const int cg = (l & 7) ^ lrow;          // pre-swizzled global chunk
  const int lr = l & 15, lg = l >> 4;

  if (blockIdx.x < NU) {
    // ---- U-GEMM role: U = Vb @ W2^T (B = W2b), 64x64, 8 waves (32x16 each)
    const int ub = blockIdx.x;
    const int rb = ub >> 3, cb = ub & 7;
    const int row0 = rb * 64, col0 = cb * 64;
    const ushort* __restrict__ ap = Vb  + (row0 + w * 8 + lrow) * HH + cg * 8;
    const ushort* __restrict__ bp = W2b + (col0 + w * 8 + lrow) * HH + cg * 8;
    const int wm = w >> 2, wn = w & 3;

    f32x4 acc[2];
    acc[0] = (f32x4)0.f; acc[1] = (f32x4)0.f;

    // prologue: 8 waves x 8 rows = 64 rows per operand
    gload16(ap, As + w * 512);
    gload16(bp, Bs + w * 512);
    __syncthreads();

    for (int kt = 0; kt < NT; ++kt) {
      const int curA = (kt & 1) << 14, curB = (kt & 1) << 13;
      if (kt + 1 < NT) {
        const int nA = ((kt + 1) & 1) << 14, nB = ((kt + 1) & 1) << 13;
        const int koff = (kt + 1) * GBK;
        gload16(ap + koff, As + nA + w * 512);
        gload16(bp + koff, Bs + nB + w * 512);
      }
#pragma unroll
      for (int k0 = 0; k0 < GBK; k0 += 32) {
        const int ck = (k0 >> 3) + lg;
        bf16x8 af0 = *reinterpret_cast<const bf16x8*>(
            &As[curA + swz(wm * 32 + lr, ck)]);
        bf16x8 af1 = *reinterpret_cast<const bf16x8*>(
            &As[curA + swz(wm * 32 + 16 + lr, ck)]);
        bf16x8 bf = *reinterpret_cast<const bf16x8*>(
            &Bs[curB + swz(wn * 16 + lr, ck)]);
        acc[0] = __builtin_amdgcn_mfma_f32_16x16x32_bf16(af0, bf, acc[0], 0, 0, 0);
        acc[1] = __builtin_amdgcn_mfma_f32_16x16x32_bf16(af1, bf, acc[1], 0, 0, 0);
      }
      __syncthreads();
    }

#pragma unroll
    for (int m = 0; m < 2; ++m)
#pragma unroll
      for (int e = 0; e < 4; ++e) {
        const int row = row0 + wm * 32 + m * 16 + lg * 4 + e;
        const int col = col0 + wn * 16 + lr;
        float u = acc[m][e];
        float d1 = D1[row * HH + col];
        float t1 = bf2f(T1b[row * HH + col]);
        S1[row * HH + col] = d1 * u;                    // fp32 (gsq accuracy)
        C1b[row * HH + col] = f2bf(-2.f * t1 * d1 * u); // bf16 (clipped later)
      }
  } else {
    // ---- m-GEMM role: 256x128 tile. Bijective XCD swizzle (768%8==0),
    //      cb fastest so the 4 col-blocks of one A-panel share L2.
    const int bid = blockIdx.x - NU;                      // 0..MG2-1
    const int wgid = (bid & 7) * (MG2 / 8) + (bid >> 3);
    const int cb = wgid & 3;
    const int rb = wgid >> 2;                             // 0..191
    const int row0 = rb * GBM2, col0 = cb * GBN;
    // wave stages A rows w*32..w*32+31 (4 issues), B rows w*16..w*16+15 (2)
    const ushort* __restrict__ ap = Abig + (row0 + w * 32 + lrow) * HH + cg * 8;
    const ushort* __restrict__ bp = W2Tb + (col0 + w * 16 + lrow) * HH + cg * 8;
    const int wm = w >> 1, wn = w & 1;

    f32x4 acc[4][4];
#pragma unroll
    for (int m = 0; m < 4; ++m)
#pragma unroll
      for (int n = 0; n < 4; ++n) acc[m][n] = (f32x4)0.f;

    // prologue: stage K-tile 0
#pragma unroll
    for (int q = 0; q < 4; ++q)
      gload16(ap + q * 8 * HH, As + (w * 4 + q) * 512);
#pragma unroll
    for (int q = 0; q < 2; ++q)
      gload16(bp + q * 8 * HH, Bs + (w * 2 + q) * 512);
    __syncthreads();

    for (int kt = 0; kt < NT; ++kt) {
      const int curA = (kt & 1) << 14, curB = (kt & 1) << 13;
      if (kt + 1 < NT) {
        const int nA = ((kt + 1) & 1) << 14, nB = ((kt + 1) & 1) << 13;
        const int koff = (kt + 1) * GBK;
#pragma unroll
        for (int q = 0; q < 4; ++q)
          gload16(ap + koff + q * 8 * HH, As + nA + (w * 4 + q) * 512);
#pragma unroll
        for (int q = 0; q < 2; ++q)
          gload16(bp + koff + q * 8 * HH, Bs + nB + (w * 2 + q) * 512);
      }
#pragma unroll
      for (int k0 = 0; k0 < GBK; k0 += 32) {
        const int ck = (k0 >> 3) + lg;
        bf16x8 af[4], bfr[4];
#pragma unroll
        for (int m = 0; m < 4; ++m)
          af[m] = *reinterpret_cast<const bf16x8*>(
              &As[curA + swz(wm * 64 + m * 16 + lr, ck)]);
#pragma unroll
        for (int n = 0; n < 4; ++n)
          bfr[n] = *reinterpret_cast<const bf16x8*>(
              &Bs[curB + swz(wn * 64 + n * 16 + lr, ck)]);
#pragma unroll
        for (int m = 0; m < 4; ++m)
#pragma unroll
          for (int n = 0; n < 4; ++n)
            acc[m][n] = __builtin_amdgcn_mfma_f32_16x16x32_bf16(af[m], bfr[n],
                                                                acc[m][n], 0, 0, 0);
      }
      __syncthreads();
    }

    // fused epilogue: HD2P[cb][row] = sum_{k in col-block} C2[b,k]*m^2
#pragma unroll
    for (int m = 0; m < 4; ++m) {
#pragma unroll
      for (int e = 0; e < 4; ++e) {
        const int row_g = row0 + wm * 64 + m * 16 + lg * 4 + e;
        const int bs2 = row_g / DD;
        const float* __restrict__ c2p = &C2[bs2 * HH + col0 + wn * 64 + lr];
        float s = 0.f;
#pragma unroll
        for (int n = 0; n < 4; ++n) {
          float mv = acc[m][n][e];
          s = fmaf(c2p[n * 16] * mv, mv, s);
        }
        s += __shfl_xor(s, 1);
        s += __shfl_xor(s, 2);
        s += __shfl_xor(s, 4);
        s += __shfl_xor(s, 8);
        if (lr == 0) HD2P[cb * ROWS + row_g] = s;
      }
    }
  }
}

// ---------------------------------------------------------------------------
// K4: per-sample grad/hdiag reduce + finalize (fp32 S1, bf16 C1)
// ---------------------------------------------------------------------------
__global__ __launch_bounds__(256) void k_grad_fin(
    const float* __restrict__ W1, const float* __restrict__ S1,
    const ushort* __restrict__ C1b, const float* __restrict__ HD2P,
    const float* __restrict__ POT, float* __restrict__ OUT) {
  const int b = blockIdx.x, tid = threadIdx.x;
  __shared__ float gtmp[DD], htmp[DD];
  const int wid = tid >> 6, lane = tid & 63;
  const int j0 = lane * 8;   // 64 lanes x 8 = 512

  for (int i = wid; i < DD; i += 4) {
    float4 wa = *reinterpret_cast<const float4*>(&W1[i * HH + j0]);
    float4 wb = *reinterpret_cast<const float4*>(&W1[i * HH + j0 + 4]);
    float4 sa = *reinterpret_cast<const float4*>(&S1[b * HH + j0]);
    float4 sb = *reinterpret_cast<const float4*>(&S1[b * HH + j0 + 4]);
    u16x8 cv = *reinterpret_cast<const u16x8*>(&C1b[b * HH + j0]);
    float wv[8] = {wa.x, wa.y, wa.z, wa.w, wb.x, wb.y, wb.z, wb.w};
    float sv[8] = {sa.x, sa.y, sa.z, sa.w, sb.x, sb.y, sb.z, sb.w};
    float gp = 0.f, hp = 0.f;
#pragma unroll
    for (int e = 0; e < 8; ++e) {
      gp = fmaf(wv[e], sv[e], gp);
      hp = fmaf(wv[e] * wv[e], bf2f(cv[e]), hp);
    }
#pragma unroll
    for (int off = 32; off > 0; off >>= 1) {
      gp += __shfl_down(gp, off);
      hp += __shfl_down(hp, off);
    }
    if (lane == 0) { gtmp[i] = gp; htmp[i] = hp; }
  }
  __syncthreads();

  if (tid < 64) {
    float gv = 0.f, hv = 0.f;
    if (tid < DD) {
      gv = gtmp[tid];
      float h = htmp[tid];
#pragma unroll
      for (int c = 0; c < NCB; ++c) h += HD2P[c * ROWS + b * DD + tid];
      if (h >= -1e30f && h <= 1e30f) h = fminf(fmaxf(h, -50.f), 50.f);
      else h = 0.f;
      hv = h;
    }
    float sq = gv * gv;
#pragma unroll
    for (int off = 32; off > 0; off >>= 1) {
      sq += __shfl_down(sq, off);
      hv += __shfl_down(hv, off);
    }
    if (tid == 0) {
      float kin = fminf(fmaxf(-0.5f * (hv + sq), -100.f), 100.f);
      OUT[b] = kin + POT[b];
    }
  }
}

// ---------------------------------------------------------------------------
// Workspace layout — sizes in FLOAT-SLOTS, non-overlapping (verified R9/R10).
//   W2b   @       0  (131072)   W2Tb @ 131072 (131072)
//   T1b   @  262144  (262144)   Vb   @ 524288 (262144)   C1b @ 786432 (262144)
//   S1    @ 1048576  (524288)   D1   @ 1572864 (524288)  C2  @ 2097152 (524288)
//   POT   @ 2621440  (1024)     HD2P @ 2622464 (196608)
//   Abig  @ 2819072  (12582912)  end: 15401984 fl = 61.6MB
// ---------------------------------------------------------------------------
extern "C" void kernel_launch(void* const* d_in, const int* in_sizes, int n_in,
                              void* d_out, int out_size, void* d_ws, size_t ws_size,
                              hipStream_t stream) {
  const float* X    = (const float*)d_in[0];  // [1024,16,3]
  const float* ATOM = (const float*)d_in[1];  // [4,3]
  const float* Z    = (const float*)d_in[2];  // [4]
  const float* W1   = (const float*)d_in[3];  // [48,512]
  const float* B1   = (const float*)d_in[4];  // [512]
  const float* W2   = (const float*)d_in[5];  // [512,512]
  const float* B2   = (const float*)d_in[6];  // [512]
  const float* w3   = (const float*)d_in[7];  // [512]
  float* out = (float*)d_out;

  float* ws = (float*)d_ws;
  ushort* W2b  = (ushort*)(ws + 0);
  ushort* W2Tb = (ushort*)(ws + 131072);
  ushort* T1b  = (ushort*)(ws + 262144);
  ushort* Vb   = (ushort*)(ws + 524288);
  ushort* C1b  = (ushort*)(ws + 786432);
  float*  S1   = ws + 1048576;
  float*  D1   = ws + 1572864;
  float*  C2   = ws + 2097152;
  float*  POT  = ws + 2621440;
  float*  HD2P = ws + 2622464;
  ushort* Abig = (ushort*)(ws + 2819072);

  k_l1pot<<<BTOT, 256, 0, stream>>>(X, ATOM, Z, W1, B1, W2, W2b, W2Tb,
                                    T1b, D1, Abig, POT);
  k_act64<<<128, 256, 0, stream>>>(T1b, W2Tb, B2, w3, C2, Vb);
  k_mu<<<NU + MG2, 512, 0, stream>>>(Abig, W2Tb, C2, HD2P,
                                     Vb, W2b, D1, T1b, S1, C1b);
  k_grad_fin<<<BTOT, 256, 0, stream>>>(W1, S1, C1b, HD2P, POT, out);
}